// Round 1
// baseline (5445.298 us; speedup 1.0000x reference)
//
#include <hip/hip_runtime.h>
#include <hip/hip_bf16.h>
#include <stdint.h>
#include <stddef.h>

// Problem constants (B=32, T=256, E=1024, H=1024)
#define TT    256
#define NBLK  256   // persistent blocks: 2 waves each -> 512 waves total

typedef __attribute__((ext_vector_type(8))) short short8;
typedef __attribute__((ext_vector_type(4))) float f32x4;

// fp32 -> bf16 (RNE), bit pattern as short
__device__ __forceinline__ short f2bf(float v) {
  uint32_t u = __builtin_bit_cast(uint32_t, v);
  uint32_t r = (u + 0x7fffu + ((u >> 16) & 1u)) >> 16;
  return (short)r;
}

// ---------------------------------------------------------------------------
// K0: copy mask to output tail, zero h ping-pong buffers + barrier counter
// ---------------------------------------------------------------------------
__global__ void k_init(const float* __restrict__ mask, float* __restrict__ out,
                       uint32_t* __restrict__ hz, uint32_t* __restrict__ cnt) {
  int tid = blockIdx.x * blockDim.x + threadIdx.x;   // 16384 threads
  if (tid < 8192) out[8388608 + tid] = mask[tid];    // mask passthrough output
  for (int j = tid; j < 65536; j += 16384) hz[j] = 0; // h0[2] + h1[2] = 256KB
  if (tid == 0) *cnt = 0;
}

// ---------------------------------------------------------------------------
// K1: pack weights into bf16 MFMA-B fragment order.
// Layout: Bp[wave][s][lane][8]  (wave 0..511, s 0..63, lane 0..63, 16B chunks)
//  wave<256 -> pre0 (MA=W_ih0 for k<1024 [x part], MB=W_hh0 for k>=1024 [h0])
//  wave>=256-> pre1 (MA=W_ih1 [h0 part],            MB=W_hh1 [h1 part])
//  column permutation: local col c (0..15): precol = (c>>2)*1024 + wg*4 + (c&3)
//  (wave owns gates f,i,o,g for h-cols wg*4 .. wg*4+3 -> gating is wave-local)
//  k = s*32 + (lane>>4)*8 + j  (B-frag: n = lane&15, k = quad*8 + j)
// ---------------------------------------------------------------------------
__global__ void k_packw(const float* __restrict__ Wih0, const float* __restrict__ Whh0,
                        const float* __restrict__ Wih1, const float* __restrict__ Whh1,
                        short* __restrict__ Bp) {
  int cid = blockIdx.x * blockDim.x + threadIdx.x;   // 0 .. 2097151
  int l = cid & 63;
  int s = (cid >> 6) & 63;
  int w = cid >> 12;                                  // 0..511
  int q = l >> 4, cc = l & 15;
  int wg = w & 255;
  bool p1 = (w >= 256);
  int precol = (cc >> 2) * 1024 + wg * 4 + (cc & 3);
  const float* MA = p1 ? Wih1 : Wih0;
  const float* MB = p1 ? Whh1 : Whh0;
  short8 o;
#pragma unroll
  for (int j = 0; j < 8; ++j) {
    int k = s * 32 + q * 8 + j;                       // 0..2047
    const float* M = (k < 1024) ? MA : MB;
    o[j] = f2bf(M[(size_t)(k & 1023) * 4096 + precol]);
  }
  ((short8*)Bp)[cid] = o;
}

// ---------------------------------------------------------------------------
// K2: convert x to bf16 blocked A-layout per t: Xb[t][kb][b][8]
//  element x[b][t][e] -> Xb[ ((t*128 + e/8)*32 + b)*8 + e%8 ]
// ---------------------------------------------------------------------------
__global__ void k_packx(const float* __restrict__ x, short* __restrict__ Xb) {
  int tid = blockIdx.x * blockDim.x + threadIdx.x;   // 0 .. 1048575
  int eg = tid & 127;
  int t  = (tid >> 7) & 255;
  int b  = tid >> 15;
  const float* src = x + ((size_t)(b * 256 + t) * 1024 + eg * 8);
  short8 o;
#pragma unroll
  for (int j = 0; j < 8; ++j) o[j] = f2bf(src[j]);
  ((short8*)Xb)[(t * 128 + eg) * 32 + b] = o;
}

// ---------------------------------------------------------------------------
// K3: persistent recurrent kernel.
// 256 blocks x 128 threads. Blocks 0..127 -> pre0 (layer0), 128..255 -> pre1.
// Each wave: 16 pre-cols (4 gates x 4 h-cols), K=2048 in 2 phases of 1024.
// B resident in 256 VGPRs; A staged 64KB/phase via global_load_lds;
// c/h state fp32 in registers across all 256 steps; 1 grid barrier/step.
// ---------------------------------------------------------------------------
__global__ __launch_bounds__(128, 1) void k_lstm(
    const float* __restrict__ mask, const float* __restrict__ b0,
    const float* __restrict__ b1,   const short* __restrict__ Bp,
    const short* __restrict__ Xb,   short* __restrict__ h0b,
    short* __restrict__ h1b,        float* __restrict__ out,
    uint32_t* cnt) {
  __shared__ short Alds[32768];  // 64KB: [kb 0..127][m 0..31][8] bf16

  const int tid  = threadIdx.x;
  const int wv   = tid >> 6;       // wave in block: 0/1
  const int lane = tid & 63;
  const int quad = lane >> 4;
  const int cc   = lane & 15;
  const int bid  = blockIdx.x;
  const bool is1 = (bid >= 128);
  const int wg   = (bid & 127) * 2 + wv;           // 0..255 within group
  const int wgid = (is1 ? 256 : 0) + wg;           // global wave id 0..511
  const int n0   = wg * 4;
  const int hcol = n0 + (cc & 3);

  // Load this wave's B fragments (64KB) into registers, once.
  short8 bfr[64];
  {
    const short8* p = ((const short8*)Bp) + (size_t)wgid * 4096 + lane;
#pragma unroll
    for (int s = 0; s < 64; ++s) bfr[s] = p[s * 64];
  }
  const float* bias = is1 ? b1 : b0;
  const float bv = bias[(cc >> 2) * 1024 + n0 + (cc & 3)];

  float cst[8], hst[8];
#pragma unroll
  for (int i = 0; i < 8; ++i) { cst[i] = 0.f; hst[i] = 0.f; }

  const int shuf_base = (lane & 48) | (lane & 3);

  for (int t = 0; t < TT; ++t) {
    const int p = t & 1;  // read buffers [p], write buffers [1-p]
    f32x4 acc0 = {bv, bv, bv, bv};   // batch rows 0..15
    f32x4 acc1 = {bv, bv, bv, bv};   // batch rows 16..31

#pragma unroll
    for (int ph = 0; ph < 2; ++ph) {
      const short* src;
      if (!is1) src = (ph == 0) ? (Xb + (size_t)t * 32768) : (h0b + p * 32768);
      else      src = (ph == 0) ? (h0b + p * 32768)        : (h1b + p * 32768);
      // stage 64KB (this wave stages its 32KB half), async global->LDS
      {
        const char* g = ((const char*)src) + wv * 32768;
        char* lbase = ((char*)Alds) + wv * 32768;
#pragma unroll
        for (int i = 0; i < 32; ++i) {
          __builtin_amdgcn_global_load_lds(
              (const __attribute__((address_space(1))) void*)(g + i * 1024 + lane * 16),
              (__attribute__((address_space(3))) void*)(lbase + i * 1024),
              16, 0, 0);
        }
      }
      __syncthreads();  // drains vmcnt(0) before barrier -> LDS ready
      const short8* ap = (const short8*)Alds;
#pragma unroll
      for (int s = 0; s < 32; ++s) {
        const int kb = s * 4 + quad;
        short8 a0 = ap[kb * 32 + cc];        // A[m=cc][k=kb*8..]
        short8 a1 = ap[kb * 32 + 16 + cc];   // A[m=16+cc]
        acc0 = __builtin_amdgcn_mfma_f32_16x16x32_bf16(a0, bfr[ph * 32 + s], acc0, 0, 0, 0);
        acc1 = __builtin_amdgcn_mfma_f32_16x16x32_bf16(a1, bfr[ph * 32 + s], acc1, 0, 0, 0);
      }
      __syncthreads();  // all waves done reading before next phase restage
    }

    // ---- gating (C/D layout: col = lane&15, row = quad*4 + reg) ----
    float pv[8];
    pv[0] = acc0.x; pv[1] = acc0.y; pv[2] = acc0.z; pv[3] = acc0.w;
    pv[4] = acc1.x; pv[5] = acc1.y; pv[6] = acc1.z; pv[7] = acc1.w;
#pragma unroll
    for (int i = 0; i < 8; ++i) {
      float v = pv[i];
      float fg = __shfl(v, shuf_base + 0, 64);
      float ig = __shfl(v, shuf_base + 4, 64);
      float og = __shfl(v, shuf_base + 8, 64);
      float gg = __shfl(v, shuf_base + 12, 64);
      int r = ((i >> 2) << 4) + quad * 4 + (i & 3);   // batch row 0..31
      float m  = mask[r * 256 + t];
      float om = 1.f - m;
      float sf = 1.f / (1.f + __expf(-fg));
      float si = 1.f / (1.f + __expf(-ig));
      float so = 1.f / (1.f + __expf(-og));
      float e2 = __expf(-2.f * fabsf(gg));
      float tg = (1.f - e2) / (1.f + e2);
      tg = (gg < 0.f) ? -tg : tg;
      float c1 = sf * cst[i] + si * tg;
      c1 = c1 * m + cst[i] * om;
      float ec = __expf(-2.f * fabsf(c1));
      float tc = (1.f - ec) / (1.f + ec);
      tc = (c1 < 0.f) ? -tc : tc;
      float h1 = so * tc;
      h1 = h1 * m + hst[i] * om;
      cst[i] = c1; hst[i] = h1;
      if ((lane & 12) == 0) {  // one lane per (quad, h-col): gate-0 lanes
        int hidx = ((hcol >> 3) * 32 + r) * 8 + (hcol & 7);  // blocked layout
        short hb = f2bf(h1);
        if (!is1) {
          h0b[(1 - p) * 32768 + hidx] = hb;
        } else {
          h1b[(1 - p) * 32768 + hidx] = hb;
          out[((size_t)r * 256 + t) * 1024 + hcol] = h1;     // states[b][t][n]
        }
      }
    }

    // ---- grid barrier (monotonic epoch counter, device scope) ----
    __syncthreads();
    if (tid == 0) {
      __hip_atomic_fetch_add(cnt, 1u, __ATOMIC_RELEASE, __HIP_MEMORY_SCOPE_AGENT);
      const uint32_t target = (uint32_t)NBLK * (uint32_t)(t + 1);
      while (__hip_atomic_load(cnt, __ATOMIC_ACQUIRE, __HIP_MEMORY_SCOPE_AGENT) < target)
        __builtin_amdgcn_s_sleep(2);
    }
    __syncthreads();
  }
}

// ---------------------------------------------------------------------------
// Workspace layout (bytes):
//   [0, 32MB)            B_packed   (512 waves x 64KB bf16)
//   [32MB, 48MB)         X blocked  (8.4M bf16)
//   [48MB, +128KB)       h0 ping-pong (2 x 64KB bf16)
//   [.. , +128KB)        h1 ping-pong
//   [.. , +4B)           barrier counter
// Total ~50.6 MB.
// ---------------------------------------------------------------------------
extern "C" void kernel_launch(void* const* d_in, const int* in_sizes, int n_in,
                              void* d_out, int out_size, void* d_ws, size_t ws_size,
                              hipStream_t stream) {
  const float* x    = (const float*)d_in[0];
  const float* mask = (const float*)d_in[1];
  const float* Wih0 = (const float*)d_in[2];
  const float* Whh0 = (const float*)d_in[3];
  const float* b0   = (const float*)d_in[4];
  const float* Wih1 = (const float*)d_in[5];
  const float* Whh1 = (const float*)d_in[6];
  const float* b1   = (const float*)d_in[7];
  float* out = (float*)d_out;

  char* ws = (char*)d_ws;
  short*    Bp  = (short*)ws;
  short*    Xb  = (short*)(ws + 33554432);
  short*    h0b = (short*)(ws + 50331648);
  short*    h1b = (short*)(ws + 50462720);
  uint32_t* cnt = (uint32_t*)(ws + 50593792);

  hipLaunchKernelGGL(k_init,  dim3(64),   dim3(256), 0, stream, mask, out, (uint32_t*)h0b, cnt);
  hipLaunchKernelGGL(k_packw, dim3(8192), dim3(256), 0, stream, Wih0, Whh0, Wih1, Whh1, Bp);
  hipLaunchKernelGGL(k_packx, dim3(4096), dim3(256), 0, stream, x, Xb);
  hipLaunchKernelGGL(k_lstm,  dim3(NBLK), dim3(128), 0, stream,
                     mask, b0, b1, Bp, Xb, h0b, h1b, out, cnt);
}

// Round 2
// 5347.747 us; speedup vs baseline: 1.0182x; 1.0182x over previous
//
#include <hip/hip_runtime.h>
#include <hip/hip_bf16.h>
#include <stdint.h>
#include <stddef.h>

// Problem constants (B=32, T=256, E=H=1024)
#define TT    256
#define NBLK  128   // 128 persistent blocks x 4 waves = 512 waves

typedef __attribute__((ext_vector_type(8))) short short8;
typedef __attribute__((ext_vector_type(4))) float f32x4;

// fp32 -> bf16 (RNE)
__device__ __forceinline__ short f2bf(float v) {
  uint32_t u = __builtin_bit_cast(uint32_t, v);
  uint32_t r = (u + 0x7fffu + ((u >> 16) & 1u)) >> 16;
  return (short)r;
}

// ---------------------------------------------------------------------------
// K0: mask passthrough output; zero h ping-pong buffers + barrier block
// ---------------------------------------------------------------------------
__global__ void k_init(const float* __restrict__ mask, float* __restrict__ out,
                       uint32_t* __restrict__ z) {
  int tid = blockIdx.x * blockDim.x + threadIdx.x;   // 16384 threads
  if (tid < 8192) out[8388608 + tid] = mask[tid];
  for (int j = tid; j < 66560; j += 16384) z[j] = 0; // h0[2]+h1[2] (256KB) + bar (4KB)
}

// ---------------------------------------------------------------------------
// K1: pack weights into bf16 MFMA-B fragment order.
// Bp[wgid 0..511][f 0..63][lane 0..63][8 shorts], wgid = layer*256 + blk*4 + w
//  f = cg*16 + s;  k = w*512 + s*32 + (lane>>4)*8 + j  (B-frag: n=lane&15)
//  col = ((lane&15)>>2)*1024 + blk*16 + cg*4 + (lane&3)   (gate-interleaved)
//  k<1024 -> W_ih (x / h0-input part), k>=1024 -> W_hh (recurrent part)
// ---------------------------------------------------------------------------
__global__ void k_packw(const float* __restrict__ Wih0, const float* __restrict__ Whh0,
                        const float* __restrict__ Wih1, const float* __restrict__ Whh1,
                        short* __restrict__ Bp) {
  int cid = blockIdx.x * blockDim.x + threadIdx.x;   // 0 .. 2097151
  int l    = cid & 63;
  int f    = (cid >> 6) & 63;
  int wgid = cid >> 12;                               // 0..511
  int q  = l >> 4, cc = l & 15;
  int cg = f >> 4, s = f & 15;
  int w    = wgid & 3;
  int blk  = (wgid >> 2) & 63;
  bool p1  = (wgid >= 256);
  int precol = (cc >> 2) * 1024 + blk * 16 + cg * 4 + (cc & 3);
  const float* MA = p1 ? Wih1 : Wih0;
  const float* MB = p1 ? Whh1 : Whh0;
  short8 o;
#pragma unroll
  for (int j = 0; j < 8; ++j) {
    int k = w * 512 + s * 32 + q * 8 + j;            // 0..2047
    const float* M = (k < 1024) ? MA : MB;
    o[j] = f2bf(M[(size_t)(k & 1023) * 4096 + precol]);
  }
  ((short8*)Bp)[cid] = o;
}

// ---------------------------------------------------------------------------
// K2: convert x to bf16 blocked A-layout per t: Xb[t][kb][m=b][8]
// ---------------------------------------------------------------------------
__global__ void k_packx(const float* __restrict__ x, short* __restrict__ Xb) {
  int tid = blockIdx.x * blockDim.x + threadIdx.x;   // 0 .. 1048575
  int eg = tid & 127;
  int t  = (tid >> 7) & 255;
  int b  = tid >> 15;
  const float* src = x + ((size_t)(b * 256 + t) * 1024 + eg * 8);
  short8 o;
#pragma unroll
  for (int j = 0; j < 8; ++j) o[j] = f2bf(src[j]);
  ((short8*)Xb)[(t * 128 + eg) * 32 + b] = o;
}

// ---------------------------------------------------------------------------
// K3: persistent recurrent kernel. 128 blocks x 256 threads (4 waves).
// bid<64 -> layer0, bid>=64 -> layer1. Block owns 64 pre-cols (16 h-cols x 4
// gates). Wave wv computes K-slice [wv*512,(wv+1)*512) for all 64 cols; the
// slice maps exactly to one source panel (wv<2: input part, wv>=2: recurrent
// part). A frags loaded global->VGPR directly (no LDS staging). Partial sums
// exchanged through 32KB LDS; wave wv gates cols cg==wv. One grid barrier
// per step: 16 group counters -> master -> epoch flag, relaxed spin.
// ---------------------------------------------------------------------------
__global__ __launch_bounds__(256, 1) void k_lstm(
    const float* __restrict__ mask, const float* __restrict__ b0,
    const float* __restrict__ b1,   const short* __restrict__ Bp,
    const short* __restrict__ Xb,   short* __restrict__ h0b,
    short* __restrict__ h1b,        float* __restrict__ out,
    uint32_t* bar) {
  __shared__ f32x4 xch[4][4][2][64];   // [writer][cg][half][lane] = 32KB

  const int tid  = threadIdx.x;
  const int wv   = tid >> 6;          // wave 0..3 (K-slice)
  const int lane = tid & 63;
  const int quad = lane >> 4;
  const int cc   = lane & 15;
  const int bid  = blockIdx.x;
  const bool is1 = (bid >= 64);
  const int blk  = bid & 63;
  const int wgid = (is1 ? 256 : 0) + blk * 4 + wv;
  const int n0w  = blk * 16 + wv * 4;             // h-col base for gating
  const int hcol = n0w + (cc & 3);
  const int kb0  = (wv & 1) * 64;                 // kb offset within source panel

  // B fragments (64 KB) resident in registers
  short8 bfr[64];
  {
    const short8* pB = ((const short8*)Bp) + (size_t)wgid * 4096 + lane;
#pragma unroll
    for (int f = 0; f < 64; ++f) bfr[f] = pB[f * 64];
  }
  const float* bias = is1 ? b1 : b0;
  const float bv = bias[(cc >> 2) * 1024 + n0w + (cc & 3)];

  float cst[8], hst[8];
#pragma unroll
  for (int i = 0; i < 8; ++i) { cst[i] = 0.f; hst[i] = 0.f; }

  const int shuf_base = (lane & 48) | (lane & 3);
  const short8* Xq = (const short8*)Xb;
  const short8* H0 = (const short8*)h0b;
  const short8* H1 = (const short8*)h1b;

  for (int t = 0; t < TT; ++t) {
    const int p = t & 1;   // read parity; write 1-p

    // source panel for this wave's K-slice
    const short8* pan;
    if (!is1) pan = (wv < 2) ? (Xq + (size_t)t * 4096) : (H0 + p * 4096);
    else      pan = (wv < 2) ? (H0 + p * 4096)         : (H1 + p * 4096);

    f32x4 acc[4][2];
#pragma unroll
    for (int cg = 0; cg < 4; ++cg) { acc[cg][0] = (f32x4)0.f; acc[cg][1] = (f32x4)0.f; }

    // mask rows for gating (static data; loads pipeline with A loads)
    float mrow[8];
#pragma unroll
    for (int i = 0; i < 8; ++i) {
      int r = ((i >> 2) << 4) + quad * 4 + (i & 3);
      mrow[i] = mask[r * 256 + t];
    }

#pragma unroll
    for (int s = 0; s < 16; ++s) {
      const short8* ap = pan + ((kb0 + s * 4 + quad) * 32 + cc);
      short8 a0 = ap[0];     // rows 0..15
      short8 a1 = ap[16];    // rows 16..31
#pragma unroll
      for (int cg = 0; cg < 4; ++cg) {
        acc[cg][0] = __builtin_amdgcn_mfma_f32_16x16x32_bf16(a0, bfr[cg * 16 + s], acc[cg][0], 0, 0, 0);
        acc[cg][1] = __builtin_amdgcn_mfma_f32_16x16x32_bf16(a1, bfr[cg * 16 + s], acc[cg][1], 0, 0, 0);
      }
    }

    // ---- cross-wave K-reduction via LDS ----
#pragma unroll
    for (int cg = 0; cg < 4; ++cg) {
      if (cg != wv) {
        xch[wv][cg][0][lane] = acc[cg][0];
        xch[wv][cg][1][lane] = acc[cg][1];
      }
    }
    __syncthreads();
    f32x4 s0 = acc[wv][0], s1 = acc[wv][1];
#pragma unroll
    for (int w2 = 0; w2 < 4; ++w2) {
      if (w2 != wv) {
        s0 += xch[w2][wv][0][lane];
        s1 += xch[w2][wv][1][lane];
      }
    }

    float pv[8];
    pv[0] = s0.x + bv; pv[1] = s0.y + bv; pv[2] = s0.z + bv; pv[3] = s0.w + bv;
    pv[4] = s1.x + bv; pv[5] = s1.y + bv; pv[6] = s1.z + bv; pv[7] = s1.w + bv;

    // ---- gating (C/D: col = lane&15, row = quad*4 + reg) ----
#pragma unroll
    for (int i = 0; i < 8; ++i) {
      float v = pv[i];
      float fg = __shfl(v, shuf_base + 0, 64);
      float ig = __shfl(v, shuf_base + 4, 64);
      float og = __shfl(v, shuf_base + 8, 64);
      float gg = __shfl(v, shuf_base + 12, 64);
      int r = ((i >> 2) << 4) + quad * 4 + (i & 3);
      float m  = mrow[i];
      float om = 1.f - m;
      float sf = 1.f / (1.f + __expf(-fg));
      float si = 1.f / (1.f + __expf(-ig));
      float so = 1.f / (1.f + __expf(-og));
      float e2 = __expf(-2.f * fabsf(gg));
      float tg = (1.f - e2) / (1.f + e2);
      tg = (gg < 0.f) ? -tg : tg;
      float c1 = sf * cst[i] + si * tg;
      c1 = c1 * m + cst[i] * om;
      float ec = __expf(-2.f * fabsf(c1));
      float tc = (1.f - ec) / (1.f + ec);
      tc = (c1 < 0.f) ? -tc : tc;
      float h1 = so * tc;
      h1 = h1 * m + hst[i] * om;
      cst[i] = c1; hst[i] = h1;
      if ((lane & 12) == 0) {   // gate-f lanes: one writer per (h-col, row)
        int hidx = ((hcol >> 3) * 32 + r) * 8 + (hcol & 7);
        short hb = f2bf(h1);
        if (!is1) {
          h0b[(1 - p) * 32768 + hidx] = hb;
        } else {
          h1b[(1 - p) * 32768 + hidx] = hb;
          out[((size_t)r * 256 + t) * 1024 + hcol] = h1;
        }
      }
    }

    // ---- grid barrier: group counters -> master -> epoch ----
    __syncthreads();   // drains vmcnt: all waves' h/out stores are in L2
    if (tid == 0) {
      uint32_t old = __hip_atomic_fetch_add(&bar[(bid & 15) * 16], 1u,
                                            __ATOMIC_RELEASE, __HIP_MEMORY_SCOPE_AGENT);
      if ((old & 7) == 7) {   // last of 8 in group this step
        uint32_t mo = __hip_atomic_fetch_add(&bar[512], 1u,
                                             __ATOMIC_ACQ_REL, __HIP_MEMORY_SCOPE_AGENT);
        if ((mo & 15) == 15)  // last group
          __hip_atomic_store(&bar[768], (uint32_t)(t + 1),
                             __ATOMIC_RELEASE, __HIP_MEMORY_SCOPE_AGENT);
      }
      const uint32_t target = (uint32_t)(t + 1);
      int it = 0;
      while (__hip_atomic_load(&bar[768], __ATOMIC_RELAXED, __HIP_MEMORY_SCOPE_AGENT) < target) {
        __builtin_amdgcn_s_sleep(1);
        if ((++it & 255) == 0)   // anti-hang insurance: periodic acquire
          (void)__hip_atomic_load(&bar[768], __ATOMIC_ACQUIRE, __HIP_MEMORY_SCOPE_AGENT);
      }
    }
    __syncthreads();
    __builtin_amdgcn_fence(__ATOMIC_ACQUIRE, "agent");  // invalidate L1/L2 once per wave
  }
}

// ---------------------------------------------------------------------------
// Workspace layout (bytes):
//   [0, 32MB)        B_packed (512 waves x 64KB bf16)
//   [32MB, 48MB)     X blocked
//   [48MB, +128KB)   h0 ping-pong
//   [..,  +128KB)    h1 ping-pong
//   [..,  +4KB)      barrier block (group counters / master / epoch)
// ---------------------------------------------------------------------------
extern "C" void kernel_launch(void* const* d_in, const int* in_sizes, int n_in,
                              void* d_out, int out_size, void* d_ws, size_t ws_size,
                              hipStream_t stream) {
  const float* x    = (const float*)d_in[0];
  const float* mask = (const float*)d_in[1];
  const float* Wih0 = (const float*)d_in[2];
  const float* Whh0 = (const float*)d_in[3];
  const float* b0   = (const float*)d_in[4];
  const float* Wih1 = (const float*)d_in[5];
  const float* Whh1 = (const float*)d_in[6];
  const float* b1   = (const float*)d_in[7];
  float* out = (float*)d_out;

  char* ws = (char*)d_ws;
  short*    Bp  = (short*)ws;
  short*    Xb  = (short*)(ws + 33554432);
  short*    h0b = (short*)(ws + 50331648);
  short*    h1b = (short*)(ws + 50462720);
  uint32_t* bar = (uint32_t*)(ws + 50593792);

  hipLaunchKernelGGL(k_init,  dim3(64),   dim3(256), 0, stream, mask, out, (uint32_t*)h0b);
  hipLaunchKernelGGL(k_packw, dim3(8192), dim3(256), 0, stream, Wih0, Whh0, Wih1, Whh1, Bp);
  hipLaunchKernelGGL(k_packx, dim3(4096), dim3(256), 0, stream, x, Xb);
  hipLaunchKernelGGL(k_lstm,  dim3(NBLK), dim3(256), 0, stream,
                     mask, b0, b1, Bp, Xb, h0b, h1b, out, bar);
}

// Round 3
// 3813.051 us; speedup vs baseline: 1.4281x; 1.4025x over previous
//
#include <hip/hip_runtime.h>
#include <hip/hip_bf16.h>
#include <stdint.h>
#include <stddef.h>

// Problem constants (B=32, T=256, E=H=1024)
#define TT    256
#define NBLK  128   // 128 persistent blocks x 4 waves = 512 waves

typedef __attribute__((ext_vector_type(8))) short short8;
typedef __attribute__((ext_vector_type(4))) float f32x4;

// fp32 -> bf16 (RNE)
__device__ __forceinline__ short f2bf(float v) {
  uint32_t u = __builtin_bit_cast(uint32_t, v);
  uint32_t r = (u + 0x7fffu + ((u >> 16) & 1u)) >> 16;
  return (short)r;
}

// MALL-coherent (sc0+sc1, no cache-maintenance) 16B load as short8
__device__ __forceinline__ short8 ld_coh16(const void* p) {
  const uint64_t* q = (const uint64_t*)p;
  union { uint64_t u[2]; short8 s; } v;
  v.u[0] = __hip_atomic_load(q,     __ATOMIC_RELAXED, __HIP_MEMORY_SCOPE_AGENT);
  v.u[1] = __hip_atomic_load(q + 1, __ATOMIC_RELAXED, __HIP_MEMORY_SCOPE_AGENT);
  return v.s;
}

// ---------------------------------------------------------------------------
// K0: mask passthrough output; zero h ping-pong buffers + barrier block
// ---------------------------------------------------------------------------
__global__ void k_init(const float* __restrict__ mask, float* __restrict__ out,
                       uint32_t* __restrict__ z) {
  int tid = blockIdx.x * blockDim.x + threadIdx.x;   // 16384 threads
  if (tid < 8192) out[8388608 + tid] = mask[tid];
  for (int j = tid; j < 66560; j += 16384) z[j] = 0; // h0[2]+h1[2] (256KB) + bar (4KB)
}

// ---------------------------------------------------------------------------
// K1: pack weights into bf16 MFMA-B fragment order.
// Bp[wgid 0..511][f 0..63][lane 0..63][8 shorts], wgid = layer*256 + blk*4 + w
//  f = cg*16 + s;  k = w*512 + s*32 + (lane>>4)*8 + j  (B-frag: n=lane&15)
//  col = ((lane&15)>>2)*1024 + blk*16 + cg*4 + (lane&3)   (gate-interleaved)
// ---------------------------------------------------------------------------
__global__ void k_packw(const float* __restrict__ Wih0, const float* __restrict__ Whh0,
                        const float* __restrict__ Wih1, const float* __restrict__ Whh1,
                        short* __restrict__ Bp) {
  int cid = blockIdx.x * blockDim.x + threadIdx.x;   // 0 .. 2097151
  int l    = cid & 63;
  int f    = (cid >> 6) & 63;
  int wgid = cid >> 12;                               // 0..511
  int q  = l >> 4, cc = l & 15;
  int cg = f >> 4, s = f & 15;
  int w    = wgid & 3;
  int blk  = (wgid >> 2) & 63;
  bool p1  = (wgid >= 256);
  int precol = (cc >> 2) * 1024 + blk * 16 + cg * 4 + (cc & 3);
  const float* MA = p1 ? Wih1 : Wih0;
  const float* MB = p1 ? Whh1 : Whh0;
  short8 o;
#pragma unroll
  for (int j = 0; j < 8; ++j) {
    int k = w * 512 + s * 32 + q * 8 + j;            // 0..2047
    const float* M = (k < 1024) ? MA : MB;
    o[j] = f2bf(M[(size_t)(k & 1023) * 4096 + precol]);
  }
  ((short8*)Bp)[cid] = o;
}

// ---------------------------------------------------------------------------
// K2: convert x to bf16 blocked A-layout per t: Xb[t][kb][m=b][8]
// ---------------------------------------------------------------------------
__global__ void k_packx(const float* __restrict__ x, short* __restrict__ Xb) {
  int tid = blockIdx.x * blockDim.x + threadIdx.x;   // 0 .. 1048575
  int eg = tid & 127;
  int t  = (tid >> 7) & 255;
  int b  = tid >> 15;
  const float* src = x + ((size_t)(b * 256 + t) * 1024 + eg * 8);
  short8 o;
#pragma unroll
  for (int j = 0; j < 8; ++j) o[j] = f2bf(src[j]);
  ((short8*)Xb)[(t * 128 + eg) * 32 + b] = o;
}

// ---------------------------------------------------------------------------
// K3: persistent recurrent kernel. 128 blocks x 256 threads (4 waves).
// bid<64 -> layer0, bid>=64 -> layer1. Block owns 64 pre-cols (16 h-cols x 4
// gates). Wave wv computes K-slice [wv*512,(wv+1)*512). A frags from Xb via
// normal cached loads; h panels via MALL-coherent relaxed atomics (sc0 sc1)
// -- NO agent fences / buffer_wbl2 / buffer_inv anywhere in the loop.
// h written via LDS repack -> contiguous 1KB -> wave0 packed coherent stores.
// Grid barrier: relaxed fan-in (16 group ctrs -> master -> epoch), relaxed
// spin; ordering by vmcnt drain (__syncthreads) + RMW data dependencies.
// ---------------------------------------------------------------------------
__global__ __launch_bounds__(256, 1) void k_lstm(
    const float* __restrict__ mask, const float* __restrict__ b0,
    const float* __restrict__ b1,   const short* __restrict__ Bp,
    const short* __restrict__ Xb,   short* __restrict__ h0b,
    short* __restrict__ h1b,        float* __restrict__ out,
    uint32_t* bar) {
  __shared__ f32x4 xch[4][4][2][64];   // 32KB partial-sum exchange
  __shared__ short hstage[512];        // 1KB h repack staging

  const int tid  = threadIdx.x;
  const int wv   = tid >> 6;          // wave 0..3 (K-slice)
  const int lane = tid & 63;
  const int quad = lane >> 4;
  const int cc   = lane & 15;
  const int bid  = blockIdx.x;
  const bool is1 = (bid >= 64);
  const int blk  = bid & 63;
  const int wgid = (is1 ? 256 : 0) + blk * 4 + wv;
  const int n0w  = blk * 16 + wv * 4;             // h-col base for gating
  const int hcol = n0w + (cc & 3);
  const int kb0  = (wv & 1) * 64;                 // kb offset within source panel
  const bool coh = !(!is1 && wv < 2);             // this wave's A-source is an h panel

  // B fragments (64 KB) resident in registers
  short8 bfr[64];
  {
    const short8* pB = ((const short8*)Bp) + (size_t)wgid * 4096 + lane;
#pragma unroll
    for (int f = 0; f < 64; ++f) bfr[f] = pB[f * 64];
  }
  const float* bias = is1 ? b1 : b0;
  const float bv = bias[(cc >> 2) * 1024 + n0w + (cc & 3)];

  float cst[8], hst[8];
#pragma unroll
  for (int i = 0; i < 8; ++i) { cst[i] = 0.f; hst[i] = 0.f; }

  const int shuf_base = (lane & 48) | (lane & 3);
  const short8* Xq = (const short8*)Xb;
  const short8* H0 = (const short8*)h0b;
  const short8* H1 = (const short8*)h1b;

  for (int t = 0; t < TT; ++t) {
    const int p = t & 1;   // read parity; write 1-p

    const short8* pan;
    if (!is1) pan = (wv < 2) ? (Xq + (size_t)t * 4096) : (H0 + p * 4096);
    else      pan = (wv < 2) ? (H0 + p * 4096)         : (H1 + p * 4096);

    f32x4 acc[4][2];
#pragma unroll
    for (int cg = 0; cg < 4; ++cg) { acc[cg][0] = (f32x4)0.f; acc[cg][1] = (f32x4)0.f; }

    float mrow[8];
#pragma unroll
    for (int i = 0; i < 8; ++i) {
      int r = ((i >> 2) << 4) + quad * 4 + (i & 3);
      mrow[i] = mask[r * 256 + t];
    }

    if (coh) {
#pragma unroll
      for (int s = 0; s < 16; ++s) {
        const short8* ap = pan + ((kb0 + s * 4 + quad) * 32 + cc);
        short8 a0 = ld_coh16(ap);        // rows 0..15  (MALL-coherent)
        short8 a1 = ld_coh16(ap + 16);   // rows 16..31
#pragma unroll
        for (int cg = 0; cg < 4; ++cg) {
          acc[cg][0] = __builtin_amdgcn_mfma_f32_16x16x32_bf16(a0, bfr[cg * 16 + s], acc[cg][0], 0, 0, 0);
          acc[cg][1] = __builtin_amdgcn_mfma_f32_16x16x32_bf16(a1, bfr[cg * 16 + s], acc[cg][1], 0, 0, 0);
        }
      }
    } else {
#pragma unroll
      for (int s = 0; s < 16; ++s) {
        const short8* ap = pan + ((kb0 + s * 4 + quad) * 32 + cc);
        short8 a0 = ap[0];
        short8 a1 = ap[16];
#pragma unroll
        for (int cg = 0; cg < 4; ++cg) {
          acc[cg][0] = __builtin_amdgcn_mfma_f32_16x16x32_bf16(a0, bfr[cg * 16 + s], acc[cg][0], 0, 0, 0);
          acc[cg][1] = __builtin_amdgcn_mfma_f32_16x16x32_bf16(a1, bfr[cg * 16 + s], acc[cg][1], 0, 0, 0);
        }
      }
    }

    // ---- cross-wave K-reduction via LDS ----
#pragma unroll
    for (int cg = 0; cg < 4; ++cg) {
      if (cg != wv) {
        xch[wv][cg][0][lane] = acc[cg][0];
        xch[wv][cg][1][lane] = acc[cg][1];
      }
    }
    __syncthreads();
    f32x4 s0 = acc[wv][0], s1 = acc[wv][1];
#pragma unroll
    for (int w2 = 0; w2 < 4; ++w2) {
      if (w2 != wv) {
        s0 += xch[w2][wv][0][lane];
        s1 += xch[w2][wv][1][lane];
      }
    }

    float pv[8];
    pv[0] = s0.x + bv; pv[1] = s0.y + bv; pv[2] = s0.z + bv; pv[3] = s0.w + bv;
    pv[4] = s1.x + bv; pv[5] = s1.y + bv; pv[6] = s1.z + bv; pv[7] = s1.w + bv;

    // ---- gating (C/D: col = lane&15, row = quad*4 + reg) ----
#pragma unroll
    for (int i = 0; i < 8; ++i) {
      float v = pv[i];
      float fg = __shfl(v, shuf_base + 0, 64);
      float ig = __shfl(v, shuf_base + 4, 64);
      float og = __shfl(v, shuf_base + 8, 64);
      float gg = __shfl(v, shuf_base + 12, 64);
      int r = ((i >> 2) << 4) + quad * 4 + (i & 3);
      float m  = mrow[i];
      float om = 1.f - m;
      float sf = 1.f / (1.f + __expf(-fg));
      float si = 1.f / (1.f + __expf(-ig));
      float so = 1.f / (1.f + __expf(-og));
      float e2 = __expf(-2.f * fabsf(gg));
      float tg = (1.f - e2) / (1.f + e2);
      tg = (gg < 0.f) ? -tg : tg;
      float c1 = sf * cst[i] + si * tg;
      c1 = c1 * m + cst[i] * om;
      float ec = __expf(-2.f * fabsf(c1));
      float tc = (1.f - ec) / (1.f + ec);
      tc = (c1 < 0.f) ? -tc : tc;
      float h1 = so * tc;
      h1 = h1 * m + hst[i] * om;
      cst[i] = c1; hst[i] = h1;
      if ((lane & 12) == 0) {   // gate-f lanes: one writer per (h-col, row)
        int hl = wv * 4 + (cc & 3);                 // block-local h-col 0..15
        hstage[(hl >> 3) * 256 + r * 8 + (hl & 7)] = f2bf(h1);
        if (is1) out[((size_t)r * 256 + t) * 1024 + hcol] = h1;
      }
    }

    __syncthreads();   // hstage complete; drains all waves' vmcnt
    if (wv == 0) {     // packed MALL-coherent h store: block's contiguous 1KB
      short* dst = (is1 ? h1b : h0b) + (1 - p) * 32768 + blk * 512 + lane * 8;
      const uint64_t* sl = ((const uint64_t*)hstage) + lane * 2;
      uint64_t v0 = sl[0], v1 = sl[1];
      __hip_atomic_store((uint64_t*)dst,     v0, __ATOMIC_RELAXED, __HIP_MEMORY_SCOPE_AGENT);
      __hip_atomic_store(((uint64_t*)dst) + 1, v1, __ATOMIC_RELAXED, __HIP_MEMORY_SCOPE_AGENT);
    }
    __syncthreads();   // wave0's coherent stores drained (vmcnt 0) before arrive

    // ---- grid barrier: relaxed fan-in, no cache maintenance ----
    if (tid == 0) {
      uint32_t old = __hip_atomic_fetch_add(&bar[(bid & 15) * 16], 1u,
                                            __ATOMIC_RELAXED, __HIP_MEMORY_SCOPE_AGENT);
      if ((old & 7) == 7) {   // last of 8 in group this step
        uint32_t mo = __hip_atomic_fetch_add(&bar[512], 1u,
                                             __ATOMIC_RELAXED, __HIP_MEMORY_SCOPE_AGENT);
        if ((mo & 15) == 15)  // last group -> publish epoch
          __hip_atomic_store(&bar[768], (uint32_t)(t + 1),
                             __ATOMIC_RELAXED, __HIP_MEMORY_SCOPE_AGENT);
      }
      while (__hip_atomic_load(&bar[768], __ATOMIC_RELAXED, __HIP_MEMORY_SCOPE_AGENT)
             < (uint32_t)(t + 1))
        __builtin_amdgcn_s_sleep(2);
    }
    __syncthreads();
  }
}

// ---------------------------------------------------------------------------
// Workspace layout (bytes):
//   [0, 32MB)        B_packed (512 waves x 64KB bf16)
//   [32MB, 48MB)     X blocked
//   [48MB, +128KB)   h0 ping-pong
//   [..,  +128KB)    h1 ping-pong
//   [..,  +4KB)      barrier block (group counters / master / epoch)
// ---------------------------------------------------------------------------
extern "C" void kernel_launch(void* const* d_in, const int* in_sizes, int n_in,
                              void* d_out, int out_size, void* d_ws, size_t ws_size,
                              hipStream_t stream) {
  const float* x    = (const float*)d_in[0];
  const float* mask = (const float*)d_in[1];
  const float* Wih0 = (const float*)d_in[2];
  const float* Whh0 = (const float*)d_in[3];
  const float* b0   = (const float*)d_in[4];
  const float* Wih1 = (const float*)d_in[5];
  const float* Whh1 = (const float*)d_in[6];
  const float* b1   = (const float*)d_in[7];
  float* out = (float*)d_out;

  char* ws = (char*)d_ws;
  short*    Bp  = (short*)ws;
  short*    Xb  = (short*)(ws + 33554432);
  short*    h0b = (short*)(ws + 50331648);
  short*    h1b = (short*)(ws + 50462720);
  uint32_t* bar = (uint32_t*)(ws + 50593792);

  hipLaunchKernelGGL(k_init,  dim3(64),   dim3(256), 0, stream, mask, out, (uint32_t*)h0b);
  hipLaunchKernelGGL(k_packw, dim3(8192), dim3(256), 0, stream, Wih0, Whh0, Wih1, Whh1, Bp);
  hipLaunchKernelGGL(k_packx, dim3(4096), dim3(256), 0, stream, x, Xb);
  hipLaunchKernelGGL(k_lstm,  dim3(NBLK), dim3(256), 0, stream,
                     mask, b0, b1, Bp, Xb, h0b, h1b, out, bar);
}